// Round 1
// baseline (9526.801 us; speedup 1.0000x reference)
//
#include <hip/hip_runtime.h>
#include <math.h>

#define B 1024
#define H 512
#define G4 2048      // 4*H
#define T_SRC 50
#define T_TGT 30
#define I_DIM 4

// GEMM tile config
#define BM 64        // batch rows per block
#define BKC 16       // hidden columns per block
#define BN 64        // gate columns per block = 4 gates * BKC
#define BK 16        // K tile
#define NT 256       // threads per block

__device__ __forceinline__ float sigm(float x) { return 1.0f / (1.0f + expf(-x)); }

// Fused: gates = A1 @ W1^T (+ A2 @ W2^T) (+ x @ Wih^T) + bias; then LSTM cell update.
// A1/A2: (B,512) fp32. W1/W2: (2048,512) row-major. Wih: (2048,4) or null. bias: (2048,)
// c_st: (B,512) in-place. h_out: (B,512) (must not alias A1/A2).
__global__ __launch_bounds__(NT)
void lstm_layer(const float* __restrict__ A1, const float* __restrict__ W1,
                const float* __restrict__ A2, const float* __restrict__ W2,
                const float* __restrict__ xsrc, int xstride,
                const float* __restrict__ Wih,
                const float* __restrict__ bias,
                float* __restrict__ c_st, float* __restrict__ h_out)
{
    __shared__ float As[BK][BM];   // 4 KB
    __shared__ float Ws[BK][BN];   // 4 KB
    __shared__ float Gs[BM][BN];   // 16 KB gates stash

    const int m0  = blockIdx.x * BM;    // batch tile base
    const int kc0 = blockIdx.y * BKC;   // hidden col tile base

    const int tid = threadIdx.x;
    const int tm  = tid >> 4;   // 0..15 -> rows tm*4..tm*4+3
    const int tn  = tid & 15;   // 0..15 -> cols tn*4..tn*4+3

    float acc[4][4];
#pragma unroll
    for (int r = 0; r < 4; ++r)
#pragma unroll
        for (int c = 0; c < 4; ++c) acc[r][c] = 0.f;

    // loader mapping: 256 threads -> 64 rows x 4 float4-quarters
    const int lr = tid >> 2;   // 0..63
    const int lq = tid & 3;    // 0..3
    // gate-column -> weight row: n in [0,64): j = (n>>4)*512 + kc0 + (n&15)
    const int jrow = ((lr >> 4) * H) + kc0 + (lr & 15);

    for (int pass = 0; pass < 2; ++pass) {
        const float* Ap = (pass == 0) ? A1 : A2;
        const float* Wp = (pass == 0) ? W1 : W2;
        if (Ap == nullptr) break;
        for (int k0 = 0; k0 < H; k0 += BK) {
            const float4 va = *reinterpret_cast<const float4*>(&Ap[(size_t)(m0 + lr) * H + k0 + lq * 4]);
            const float4 vw = *reinterpret_cast<const float4*>(&Wp[(size_t)jrow * H + k0 + lq * 4]);
            As[lq * 4 + 0][lr] = va.x; As[lq * 4 + 1][lr] = va.y;
            As[lq * 4 + 2][lr] = va.z; As[lq * 4 + 3][lr] = va.w;
            Ws[lq * 4 + 0][lr] = vw.x; Ws[lq * 4 + 1][lr] = vw.y;
            Ws[lq * 4 + 2][lr] = vw.z; Ws[lq * 4 + 3][lr] = vw.w;
            __syncthreads();
#pragma unroll
            for (int kk = 0; kk < BK; ++kk) {
                float4 a4 = *reinterpret_cast<const float4*>(&As[kk][tm * 4]);
                float4 w4 = *reinterpret_cast<const float4*>(&Ws[kk][tn * 4]);
                float av[4] = {a4.x, a4.y, a4.z, a4.w};
                float wv[4] = {w4.x, w4.y, w4.z, w4.w};
#pragma unroll
                for (int r = 0; r < 4; ++r)
#pragma unroll
                    for (int c = 0; c < 4; ++c) acc[r][c] += av[r] * wv[c];
            }
            __syncthreads();
        }
    }

    // stash gates tile to LDS
#pragma unroll
    for (int r = 0; r < 4; ++r) {
        float4 v = make_float4(acc[r][0], acc[r][1], acc[r][2], acc[r][3]);
        *reinterpret_cast<float4*>(&Gs[tm * 4 + r][tn * 4]) = v;
    }
    __syncthreads();

    // phase 2: cell update. 64*16 = 1024 (m,kc) items, 4 per thread.
#pragma unroll
    for (int it = 0; it < 4; ++it) {
        int id  = it * NT + tid;
        int m   = id >> 4;      // 0..63
        int kc  = id & 15;      // 0..15
        int brow = m0 + m;
        int k    = kc0 + kc;
        float gi = Gs[m][0 * BKC + kc] + bias[0 * H + k];
        float gf = Gs[m][1 * BKC + kc] + bias[1 * H + k];
        float gg = Gs[m][2 * BKC + kc] + bias[2 * H + k];
        float go = Gs[m][3 * BKC + kc] + bias[3 * H + k];
        if (Wih != nullptr) {
            const float* xr = xsrc + (size_t)brow * xstride;
            float x0 = xr[0], x1 = xr[1], x2 = xr[2], x3 = xr[3];
            const float* wi = &Wih[(size_t)(0 * H + k) * 4];
            const float* wf = &Wih[(size_t)(1 * H + k) * 4];
            const float* wg = &Wih[(size_t)(2 * H + k) * 4];
            const float* wo = &Wih[(size_t)(3 * H + k) * 4];
            gi += x0 * wi[0] + x1 * wi[1] + x2 * wi[2] + x3 * wi[3];
            gf += x0 * wf[0] + x1 * wf[1] + x2 * wf[2] + x3 * wf[3];
            gg += x0 * wg[0] + x1 * wg[1] + x2 * wg[2] + x3 * wg[3];
            go += x0 * wo[0] + x1 * wo[1] + x2 * wo[2] + x3 * wo[3];
        }
        size_t idx = (size_t)brow * H + k;
        float c_old = c_st[idx];
        float c_new = sigm(gf) * c_old + sigm(gi) * tanhf(gg);
        c_st[idx]  = c_new;
        h_out[idx] = sigm(go) * tanhf(c_new);
    }
}

// out = h1 @ head_W^T + head_b ; writes d_out[:, t, :] and dec_in
__global__ __launch_bounds__(64)
void head_kernel(const float* __restrict__ h1, const float* __restrict__ W,
                 const float* __restrict__ bias, float* __restrict__ out_t,
                 float* __restrict__ dec_in)
{
    int b = blockIdx.x;
    int lane = threadIdx.x;
    float a0 = 0.f, a1 = 0.f, a2 = 0.f, a3 = 0.f;
    for (int k = lane; k < H; k += 64) {
        float hv = h1[(size_t)b * H + k];
        a0 += hv * W[0 * H + k];
        a1 += hv * W[1 * H + k];
        a2 += hv * W[2 * H + k];
        a3 += hv * W[3 * H + k];
    }
#pragma unroll
    for (int off = 32; off; off >>= 1) {
        a0 += __shfl_down(a0, off);
        a1 += __shfl_down(a1, off);
        a2 += __shfl_down(a2, off);
        a3 += __shfl_down(a3, off);
    }
    if (lane == 0) {
        float4 v = make_float4(a0 + bias[0], a1 + bias[1], a2 + bias[2], a3 + bias[3]);
        *reinterpret_cast<float4*>(&out_t[(size_t)b * (T_TGT * I_DIM)]) = v;
        *reinterpret_cast<float4*>(&dec_in[b * 4]) = v;
    }
}

__global__ void zero_kernel(float* __restrict__ p, int n)
{
    int i = blockIdx.x * blockDim.x + threadIdx.x;
    int stride = gridDim.x * blockDim.x;
    for (; i < n; i += stride) p[i] = 0.f;
}

__global__ void init_dec(const float* __restrict__ x, float* __restrict__ dec_in)
{
    int tid = blockIdx.x * blockDim.x + threadIdx.x;
    if (tid < B * I_DIM) {
        int b = tid >> 2, i = tid & 3;
        dec_in[tid] = x[(size_t)b * (T_SRC * I_DIM) + (T_SRC - 1) * I_DIM + i];
    }
}

extern "C" void kernel_launch(void* const* d_in, const int* in_sizes, int n_in,
                              void* d_out, int out_size, void* d_ws, size_t ws_size,
                              hipStream_t stream)
{
    const float* x        = (const float*)d_in[0];
    const float* enc_Wih0 = (const float*)d_in[1];
    const float* enc_Whh0 = (const float*)d_in[2];
    const float* enc_b0   = (const float*)d_in[3];
    const float* enc_Wih1 = (const float*)d_in[4];
    const float* enc_Whh1 = (const float*)d_in[5];
    const float* enc_b1   = (const float*)d_in[6];
    const float* dec_Wih0 = (const float*)d_in[7];
    const float* dec_Whh0 = (const float*)d_in[8];
    const float* dec_b0   = (const float*)d_in[9];
    const float* dec_Wih1 = (const float*)d_in[10];
    const float* dec_Whh1 = (const float*)d_in[11];
    const float* dec_b1   = (const float*)d_in[12];
    const float* head_W   = (const float*)d_in[13];
    const float* head_b   = (const float*)d_in[14];
    float* out = (float*)d_out;

    // workspace layout (fp32)
    const size_t SZ = (size_t)B * H;       // 524288 floats
    float* ws   = (float*)d_ws;
    float* h0[2] = {ws, ws + SZ};
    float* h1[2] = {ws + 2 * SZ, ws + 3 * SZ};
    float* c0   = ws + 4 * SZ;
    float* c1   = ws + 5 * SZ;
    float* dec_in_buf = ws + 6 * SZ;       // B*4

    // zero states (h0[0], h0[1], h1[0], h1[1], c0, c1)
    zero_kernel<<<2048, 256, 0, stream>>>(ws, (int)(6 * SZ));
    init_dec<<<(B * I_DIM + 255) / 256, 256, 0, stream>>>(x, dec_in_buf);

    dim3 grid(B / BM, H / BKC);   // (16, 32) = 512 blocks
    int p = 0;

    // encoder
    for (int t = 0; t < T_SRC; ++t) {
        lstm_layer<<<grid, NT, 0, stream>>>(h0[p], enc_Whh0, nullptr, nullptr,
                                            x + (size_t)t * I_DIM, T_SRC * I_DIM, enc_Wih0,
                                            enc_b0, c0, h0[1 - p]);
        lstm_layer<<<grid, NT, 0, stream>>>(h0[1 - p], enc_Wih1, h1[p], enc_Whh1,
                                            nullptr, 0, nullptr,
                                            enc_b1, c1, h1[1 - p]);
        p ^= 1;
    }

    // decoder
    for (int t = 0; t < T_TGT; ++t) {
        lstm_layer<<<grid, NT, 0, stream>>>(h0[p], dec_Whh0, nullptr, nullptr,
                                            dec_in_buf, I_DIM, dec_Wih0,
                                            dec_b0, c0, h0[1 - p]);
        lstm_layer<<<grid, NT, 0, stream>>>(h0[1 - p], dec_Wih1, h1[p], dec_Whh1,
                                            nullptr, 0, nullptr,
                                            dec_b1, c1, h1[1 - p]);
        head_kernel<<<B, 64, 0, stream>>>(h1[1 - p], head_W, head_b,
                                          out + (size_t)t * I_DIM, dec_in_buf);
        p ^= 1;
    }
}

// Round 2
// 1973.929 us; speedup vs baseline: 4.8263x; 4.8263x over previous
//
#include <hip/hip_runtime.h>
#include <math.h>
#include <stdint.h>

#define B 1024
#define H 512
#define T_SRC 50
#define T_TGT 30
#define I_DIM 4

#define BMT 64       // batch rows per block
#define BNT 64       // gate cols per block (4 gates x 16 hidden)
#define BKT 64       // K per tile
#define NTHR 256     // 4 waves

typedef _Float16 half8 __attribute__((ext_vector_type(8)));
typedef float f32x4 __attribute__((ext_vector_type(4)));

#define GLOBAL_AS __attribute__((address_space(1)))
#define LDS_AS    __attribute__((address_space(3)))

__device__ __forceinline__ float sigm(float x) { return 1.0f / (1.0f + expf(-x)); }

// gates = A1 @ W1^T (+ A2 @ W2^T) [f16 MFMA, fp32 accum] (+ x @ Wih^T + b) [fp32]; LSTM cell.
// A*: (B,512) f16. W*: (2048,512) f16 row-major. Block covers 64 batch x (4 gates x 16 hidden cols).
__global__ __launch_bounds__(NTHR)
void lstm_f16(const _Float16* __restrict__ A1, const _Float16* __restrict__ W1,
              const _Float16* __restrict__ A2, const _Float16* __restrict__ W2,
              int npass,
              const float* __restrict__ xsrc, int xstride,
              const float* __restrict__ Wih,
              const float* __restrict__ bias,
              float* __restrict__ c_st, _Float16* __restrict__ h_out)
{
    __shared__ __align__(16) char smem[32768];   // buf[2] x (A 8K + B 8K)
    const int tid = threadIdx.x;
    const int w = tid >> 6, l = tid & 63;
    const int m0  = blockIdx.x * BMT;
    const int kc0 = blockIdx.y * 16;

    const int mw = (w & 1) * 32;   // wave row base
    const int nw = (w >> 1) * 32;  // wave col base

    f32x4 acc[2][2] = {};

    // staging: per wave 2 A-chunks + 2 B-chunks of 1KB (64 lanes x 16B) per tile.
    // LDS row = 128B (64 f16); granule (16B) XOR-swizzled by (row&7).
    int   rowq[2];
    size_t aoff[2], boff[2];   // element offsets excluding k-tile offset
#pragma unroll
    for (int q = 0; q < 2; ++q) {
        rowq[q] = (w * 2 + q) * 8 + (l >> 3);
        int gsrc = (l & 7) ^ (rowq[q] & 7);
        aoff[q] = (size_t)(m0 + rowq[q]) * H + gsrc * 8;
        int jg  = (rowq[q] >> 4) * H + kc0 + (rowq[q] & 15);  // gate-row mapping
        boff[q] = (size_t)jg * H + gsrc * 8;
    }

    const int nt = npass * 8;

    auto stage = [&](int t, int cur) {
        const _Float16* Ap = (t < 8) ? A1 : A2;
        const _Float16* Wp = (t < 8) ? W1 : W2;
        const int koff = (t & 7) * BKT;
        char* dbase = smem + cur * 16384;
#pragma unroll
        for (int q = 0; q < 2; ++q) {
            __builtin_amdgcn_global_load_lds(
                (const GLOBAL_AS uint32_t*)(Ap + aoff[q] + koff),
                (LDS_AS uint32_t*)(dbase + (w * 2 + q) * 1024), 16, 0, 0);
            __builtin_amdgcn_global_load_lds(
                (const GLOBAL_AS uint32_t*)(Wp + boff[q] + koff),
                (LDS_AS uint32_t*)(dbase + 8192 + (w * 2 + q) * 1024), 16, 0, 0);
        }
    };

    stage(0, 0);
    __syncthreads();
    int cur = 0;
    for (int t = 0; t < nt; ++t) {
        if (t + 1 < nt) stage(t + 1, cur ^ 1);   // prefetch overlaps compute
        const char* ab = smem + cur * 16384;
        const char* bb = ab + 8192;
#pragma unroll
        for (int ks = 0; ks < 2; ++ks) {
            half8 af[2], bf[2];
#pragma unroll
            for (int f = 0; f < 2; ++f) {
                const int gg = ks * 4 + (l >> 4);
                const int m = mw + f * 16 + (l & 15);
                af[f] = *reinterpret_cast<const half8*>(ab + m * 128 + ((gg ^ (m & 7)) * 16));
                const int n = nw + f * 16 + (l & 15);
                bf[f] = *reinterpret_cast<const half8*>(bb + n * 128 + ((gg ^ (n & 7)) * 16));
            }
#pragma unroll
            for (int fm = 0; fm < 2; ++fm)
#pragma unroll
                for (int fn = 0; fn < 2; ++fn)
                    acc[fm][fn] = __builtin_amdgcn_mfma_f32_16x16x32_f16(
                        af[fm], bf[fn], acc[fm][fn], 0, 0, 0);
        }
        __syncthreads();   // drains vmcnt for the prefetched tile + protects buffer reuse
        cur ^= 1;
    }

    // stash gates (fp32) to LDS, padded stride 65
    float* Gs = reinterpret_cast<float*>(smem);
#pragma unroll
    for (int fm = 0; fm < 2; ++fm)
#pragma unroll
        for (int fn = 0; fn < 2; ++fn)
#pragma unroll
            for (int r = 0; r < 4; ++r)
                Gs[(mw + fm * 16 + (l >> 4) * 4 + r) * 65 + nw + fn * 16 + (l & 15)] =
                    acc[fm][fn][r];
    __syncthreads();

    // cell update: 64x16 (m,kc) items, 4 per thread
#pragma unroll
    for (int it = 0; it < 4; ++it) {
        int id = it * NTHR + tid;
        int m = id >> 4, kc = id & 15;
        int brow = m0 + m;
        int k = kc0 + kc;
        float gi = Gs[m * 65 + 0 * 16 + kc] + bias[0 * H + k];
        float gf = Gs[m * 65 + 1 * 16 + kc] + bias[1 * H + k];
        float gg = Gs[m * 65 + 2 * 16 + kc] + bias[2 * H + k];
        float go = Gs[m * 65 + 3 * 16 + kc] + bias[3 * H + k];
        if (Wih != nullptr) {
            const float* xr = xsrc + (size_t)brow * xstride;
            float x0 = xr[0], x1 = xr[1], x2 = xr[2], x3 = xr[3];
            const float* wi = &Wih[(size_t)(0 * H + k) * 4];
            const float* wf = &Wih[(size_t)(1 * H + k) * 4];
            const float* wg = &Wih[(size_t)(2 * H + k) * 4];
            const float* wo = &Wih[(size_t)(3 * H + k) * 4];
            gi += x0 * wi[0] + x1 * wi[1] + x2 * wi[2] + x3 * wi[3];
            gf += x0 * wf[0] + x1 * wf[1] + x2 * wf[2] + x3 * wf[3];
            gg += x0 * wg[0] + x1 * wg[1] + x2 * wg[2] + x3 * wg[3];
            go += x0 * wo[0] + x1 * wo[1] + x2 * wo[2] + x3 * wo[3];
        }
        size_t idx = (size_t)brow * H + k;
        float c_old = c_st[idx];
        float c_new = sigm(gf) * c_old + sigm(gi) * tanhf(gg);
        c_st[idx] = c_new;
        h_out[idx] = (_Float16)(sigm(go) * tanhf(c_new));
    }
}

// out = h1 @ head_W^T + head_b (fp32 math, f16 h input)
__global__ __launch_bounds__(64)
void head_kernel(const _Float16* __restrict__ h1, const float* __restrict__ W,
                 const float* __restrict__ bias, float* __restrict__ out_t,
                 float* __restrict__ dec_in)
{
    int b = blockIdx.x;
    int lane = threadIdx.x;
    float a0 = 0.f, a1 = 0.f, a2 = 0.f, a3 = 0.f;
    for (int k = lane; k < H; k += 64) {
        float hv = (float)h1[(size_t)b * H + k];
        a0 += hv * W[0 * H + k];
        a1 += hv * W[1 * H + k];
        a2 += hv * W[2 * H + k];
        a3 += hv * W[3 * H + k];
    }
#pragma unroll
    for (int off = 32; off; off >>= 1) {
        a0 += __shfl_down(a0, off);
        a1 += __shfl_down(a1, off);
        a2 += __shfl_down(a2, off);
        a3 += __shfl_down(a3, off);
    }
    if (lane == 0) {
        float4 v = make_float4(a0 + bias[0], a1 + bias[1], a2 + bias[2], a3 + bias[3]);
        *reinterpret_cast<float4*>(&out_t[(size_t)b * (T_TGT * I_DIM)]) = v;
        *reinterpret_cast<float4*>(&dec_in[b * 4]) = v;
    }
}

__global__ void zero_kernel(float* __restrict__ p, int n)
{
    int i = blockIdx.x * blockDim.x + threadIdx.x;
    int stride = gridDim.x * blockDim.x;
    for (; i < n; i += stride) p[i] = 0.f;
}

__global__ void f32_to_f16(const float* __restrict__ src, _Float16* __restrict__ dst, int n)
{
    int i = blockIdx.x * blockDim.x + threadIdx.x;
    int stride = gridDim.x * blockDim.x;
    for (; i < n; i += stride) dst[i] = (_Float16)src[i];
}

__global__ void init_dec(const float* __restrict__ x, float* __restrict__ dec_in)
{
    int tid = blockIdx.x * blockDim.x + threadIdx.x;
    if (tid < B * I_DIM) {
        int b = tid >> 2, i = tid & 3;
        dec_in[tid] = x[(size_t)b * (T_SRC * I_DIM) + (T_SRC - 1) * I_DIM + i];
    }
}

extern "C" void kernel_launch(void* const* d_in, const int* in_sizes, int n_in,
                              void* d_out, int out_size, void* d_ws, size_t ws_size,
                              hipStream_t stream)
{
    const float* x        = (const float*)d_in[0];
    const float* enc_Wih0 = (const float*)d_in[1];
    const float* enc_Whh0 = (const float*)d_in[2];
    const float* enc_b0   = (const float*)d_in[3];
    const float* enc_Wih1 = (const float*)d_in[4];
    const float* enc_Whh1 = (const float*)d_in[5];
    const float* enc_b1   = (const float*)d_in[6];
    const float* dec_Wih0 = (const float*)d_in[7];
    const float* dec_Whh0 = (const float*)d_in[8];
    const float* dec_b0   = (const float*)d_in[9];
    const float* dec_Wih1 = (const float*)d_in[10];
    const float* dec_Whh1 = (const float*)d_in[11];
    const float* dec_b1   = (const float*)d_in[12];
    const float* head_W   = (const float*)d_in[13];
    const float* head_b   = (const float*)d_in[14];
    float* out = (float*)d_out;

    const size_t MB = 1u << 20;
    char* ws = (char*)d_ws;
    float*    c0        = (float*)(ws + 0 * MB);       // 2MB
    float*    c1        = (float*)(ws + 2 * MB);       // 2MB
    _Float16* h0f[2]    = {(_Float16*)(ws + 4 * MB), (_Float16*)(ws + 5 * MB)};
    _Float16* h1f[2]    = {(_Float16*)(ws + 6 * MB), (_Float16*)(ws + 7 * MB)};
    float*    dec_in_buf= (float*)(ws + 8 * MB);       // 16KB
    _Float16* eWhh0f    = (_Float16*)(ws + 9 * MB);
    _Float16* eWih1f    = (_Float16*)(ws + 11 * MB);
    _Float16* eWhh1f    = (_Float16*)(ws + 13 * MB);
    _Float16* dWhh0f    = (_Float16*)(ws + 15 * MB);
    _Float16* dWih1f    = (_Float16*)(ws + 17 * MB);
    _Float16* dWhh1f    = (_Float16*)(ws + 19 * MB);

    const int WN = 4 * H * H;  // 1M elements per weight matrix

    // zero c0,c1,h0f,h1f (8MB = 2M floats; f16 zeros are bitwise zero)
    zero_kernel<<<2048, 256, 0, stream>>>((float*)ws, (int)(8 * MB / 4));
    init_dec<<<(B * I_DIM + 255) / 256, 256, 0, stream>>>(x, dec_in_buf);
    f32_to_f16<<<1024, 256, 0, stream>>>(enc_Whh0, eWhh0f, WN);
    f32_to_f16<<<1024, 256, 0, stream>>>(enc_Wih1, eWih1f, WN);
    f32_to_f16<<<1024, 256, 0, stream>>>(enc_Whh1, eWhh1f, WN);
    f32_to_f16<<<1024, 256, 0, stream>>>(dec_Whh0, dWhh0f, WN);
    f32_to_f16<<<1024, 256, 0, stream>>>(dec_Wih1, dWih1f, WN);
    f32_to_f16<<<1024, 256, 0, stream>>>(dec_Whh1, dWhh1f, WN);

    dim3 grid(B / BMT, (4 * H) / BNT);   // (16, 32) = 512 blocks
    int p = 0;

    // encoder
    for (int t = 0; t < T_SRC; ++t) {
        lstm_f16<<<grid, NTHR, 0, stream>>>(h0f[p], eWhh0f, nullptr, nullptr, 1,
                                            x + (size_t)t * I_DIM, T_SRC * I_DIM, enc_Wih0,
                                            enc_b0, c0, h0f[1 - p]);
        lstm_f16<<<grid, NTHR, 0, stream>>>(h0f[1 - p], eWih1f, h1f[p], eWhh1f, 2,
                                            nullptr, 0, nullptr,
                                            enc_b1, c1, h1f[1 - p]);
        p ^= 1;
    }

    // decoder
    for (int t = 0; t < T_TGT; ++t) {
        lstm_f16<<<grid, NTHR, 0, stream>>>(h0f[p], dWhh0f, nullptr, nullptr, 1,
                                            dec_in_buf, I_DIM, dec_Wih0,
                                            dec_b0, c0, h0f[1 - p]);
        lstm_f16<<<grid, NTHR, 0, stream>>>(h0f[1 - p], dWih1f, h1f[p], dWhh1f, 2,
                                            nullptr, 0, nullptr,
                                            dec_b1, c1, h1f[1 - p]);
        head_kernel<<<B, 64, 0, stream>>>(h1f[1 - p], head_W, head_b,
                                          out + (size_t)t * I_DIM, dec_in_buf);
        p ^= 1;
    }
}